// Round 1
// baseline (159.128 us; speedup 1.0000x reference)
//
#include <hip/hip_runtime.h>

#define NB 32
#define NS 2048
#define NE 8
// softmax scale 1/sqrt(d_k)=0.5 folded with log2(e) so we can use v_exp_f32 (2^x)
#define QSCALE 0.72134752044448170367f

// ---------------------------------------------------------------------------
// Kernel A: per (b, q-chunk, k-slice) partial attention.
//   h = cos(x + theta); scores bounded in [-2,2] -> no max pass needed.
//   Each thread owns one query row (both heads) and accumulates
//   sum(exp(s)*v) (8 floats) + sum(exp(s)) (2 floats) over its k-slice.
// FUSED=true (single slice) normalizes + projects + writes out directly.
// ---------------------------------------------------------------------------
template <int KSLICE, bool FUSED>
__global__ __launch_bounds__(256) void attn_part_kernel(
    const float* __restrict__ x, const float* __restrict__ theta,
    const float* __restrict__ Wout, float* __restrict__ outp) {
  __shared__ float kv[KSLICE * 8];

  const int b = blockIdx.z;
  const int slice = blockIdx.y;
  const int q = blockIdx.x * 256 + threadIdx.x;
  const int k0 = slice * KSLICE;

  float th[8];
#pragma unroll
  for (int e = 0; e < 8; ++e) th[e] = theta[e];

  // Stage the k-slice of h into LDS (computed on the fly from x).
  for (int r = threadIdx.x; r < KSLICE; r += 256) {
    const float4* xr = (const float4*)(x + ((size_t)b * NS + k0 + r) * 8);
    float4 lo = xr[0], hi = xr[1];
    lo.x = __cosf(lo.x + th[0]);
    lo.y = __cosf(lo.y + th[1]);
    lo.z = __cosf(lo.z + th[2]);
    lo.w = __cosf(lo.w + th[3]);
    hi.x = __cosf(hi.x + th[4]);
    hi.y = __cosf(hi.y + th[5]);
    hi.z = __cosf(hi.z + th[6]);
    hi.w = __cosf(hi.w + th[7]);
    ((float4*)kv)[2 * r] = lo;
    ((float4*)kv)[2 * r + 1] = hi;
  }

  // This thread's query row, pre-scaled by 0.5*log2(e).
  const float4* xq = (const float4*)(x + ((size_t)b * NS + q) * 8);
  float4 qlo = xq[0], qhi = xq[1];
  qlo.x = __cosf(qlo.x + th[0]) * QSCALE;
  qlo.y = __cosf(qlo.y + th[1]) * QSCALE;
  qlo.z = __cosf(qlo.z + th[2]) * QSCALE;
  qlo.w = __cosf(qlo.w + th[3]) * QSCALE;
  qhi.x = __cosf(qhi.x + th[4]) * QSCALE;
  qhi.y = __cosf(qhi.y + th[5]) * QSCALE;
  qhi.z = __cosf(qhi.z + th[6]) * QSCALE;
  qhi.w = __cosf(qhi.w + th[7]) * QSCALE;

  __syncthreads();

  float4 a0 = {0.f, 0.f, 0.f, 0.f}, a1 = {0.f, 0.f, 0.f, 0.f};
  float d0 = 0.f, d1 = 0.f;
  const float4* kp = (const float4*)kv;
#pragma unroll 8
  for (int j = 0; j < KSLICE; ++j) {
    // All lanes read the same row -> LDS broadcast, conflict-free.
    float4 kl = kp[2 * j];
    float4 kh = kp[2 * j + 1];
    float s0 = qlo.x * kl.x + qlo.y * kl.y + qlo.z * kl.z + qlo.w * kl.w;
    float s1 = qhi.x * kh.x + qhi.y * kh.y + qhi.z * kh.z + qhi.w * kh.w;
    float p0 = __builtin_amdgcn_exp2f(s0);  // v_exp_f32
    float p1 = __builtin_amdgcn_exp2f(s1);
    a0.x += p0 * kl.x;
    a0.y += p0 * kl.y;
    a0.z += p0 * kl.z;
    a0.w += p0 * kl.w;
    d0 += p0;
    a1.x += p1 * kh.x;
    a1.y += p1 * kh.y;
    a1.z += p1 * kh.z;
    a1.w += p1 * kh.w;
    d1 += p1;
  }

  if (FUSED) {
    const float i0 = 1.0f / d0, i1 = 1.0f / d1;
    float m[8] = {a0.x * i0, a0.y * i0, a0.z * i0, a0.w * i0,
                  a1.x * i1, a1.y * i1, a1.z * i1, a1.w * i1};
    float o[8];
#pragma unroll
    for (int e = 0; e < 8; ++e) {
      float s = 0.f;
#pragma unroll
      for (int f = 0; f < 8; ++f) s += m[f] * Wout[e * 8 + f];
      o[e] = s;
    }
    float4* op = (float4*)(outp + ((size_t)b * NS + q) * 8);
    op[0] = make_float4(o[0], o[1], o[2], o[3]);
    op[1] = make_float4(o[4], o[5], o[6], o[7]);
  } else {
    // partial layout: [slice][component(10)][B*S]  (coalesced stores)
    const int idx = b * NS + q;
    float* p = outp + (size_t)slice * 10 * (NB * NS) + idx;
    p[0 * (NB * NS)] = a0.x;
    p[1 * (NB * NS)] = a0.y;
    p[2 * (NB * NS)] = a0.z;
    p[3 * (NB * NS)] = a0.w;
    p[4 * (NB * NS)] = a1.x;
    p[5 * (NB * NS)] = a1.y;
    p[6 * (NB * NS)] = a1.z;
    p[7 * (NB * NS)] = a1.w;
    p[8 * (NB * NS)] = d0;
    p[9 * (NB * NS)] = d1;
  }
}

// ---------------------------------------------------------------------------
// Kernel B: sum slice partials, normalize, apply W_out^T, write out.
// ---------------------------------------------------------------------------
__global__ __launch_bounds__(256) void attn_reduce_kernel(
    const float* __restrict__ part, const float* __restrict__ Wout,
    float* __restrict__ out, int nslice) {
  const int idx = blockIdx.x * 256 + threadIdx.x;  // 0 .. B*S-1
  float a[10];
#pragma unroll
  for (int c = 0; c < 10; ++c) a[c] = 0.f;
  for (int sl = 0; sl < nslice; ++sl) {
    const float* p = part + (size_t)sl * 10 * (NB * NS) + idx;
#pragma unroll
    for (int c = 0; c < 10; ++c) a[c] += p[c * (NB * NS)];
  }
  const float i0 = 1.0f / a[8], i1 = 1.0f / a[9];
  float m[8] = {a[0] * i0, a[1] * i0, a[2] * i0, a[3] * i0,
                a[4] * i1, a[5] * i1, a[6] * i1, a[7] * i1};
  float o[8];
#pragma unroll
  for (int e = 0; e < 8; ++e) {
    float s = 0.f;
#pragma unroll
    for (int f = 0; f < 8; ++f) s += m[f] * Wout[e * 8 + f];
    o[e] = s;
  }
  float4* op = (float4*)(out + (size_t)idx * 8);
  op[0] = make_float4(o[0], o[1], o[2], o[3]);
  op[1] = make_float4(o[4], o[5], o[6], o[7]);
}

extern "C" void kernel_launch(void* const* d_in, const int* in_sizes, int n_in,
                              void* d_out, int out_size, void* d_ws,
                              size_t ws_size, hipStream_t stream) {
  const float* x = (const float*)d_in[0];      // [32, 2048, 8]
  const float* theta = (const float*)d_in[1];  // [8]
  const float* W = (const float*)d_in[2];      // [8, 8]
  float* out = (float*)d_out;                  // [32, 2048, 8]
  float* ws = (float*)d_ws;

  const size_t per_slice = (size_t)NB * NS * 10 * sizeof(float);  // 2.62 MB

  if (ws_size >= 8 * per_slice) {
    // 8-way split-K: 2048 blocks, 8 KB LDS -> full occupancy potential.
    attn_part_kernel<256, false>
        <<<dim3(NS / 256, 8, NB), 256, 0, stream>>>(x, theta, W, ws);
    attn_reduce_kernel<<<(NB * NS) / 256, 256, 0, stream>>>(ws, W, out, 8);
  } else if (ws_size >= 4 * per_slice) {
    attn_part_kernel<512, false>
        <<<dim3(NS / 256, 4, NB), 256, 0, stream>>>(x, theta, W, ws);
    attn_reduce_kernel<<<(NB * NS) / 256, 256, 0, stream>>>(ws, W, out, 4);
  } else if (ws_size >= 2 * per_slice) {
    attn_part_kernel<1024, false>
        <<<dim3(NS / 256, 2, NB), 256, 0, stream>>>(x, theta, W, ws);
    attn_reduce_kernel<<<(NB * NS) / 256, 256, 0, stream>>>(ws, W, out, 2);
  } else {
    // Fused single-pass fallback (64 KB LDS, no workspace needed).
    attn_part_kernel<2048, true>
        <<<dim3(NS / 256, 1, NB), 256, 0, stream>>>(x, theta, W, out);
  }
}

// Round 2
// 153.714 us; speedup vs baseline: 1.0352x; 1.0352x over previous
//
#include <hip/hip_runtime.h>

#define NB 32
#define NS 2048
#define NE 8
// softmax scale 1/sqrt(d_k)=0.5 folded with log2(e) so we can use v_exp_f32 (2^x)
#define QSCALE 0.72134752044448170367f

// ---------------------------------------------------------------------------
// Kernel A: per (b, q-chunk, k-slice) partial attention, register-blocked.
//   h = cos(x + theta); scores bounded in [-2,2] -> no max pass needed.
//   Each thread owns QPT query rows (both heads) and accumulates
//   sum(exp(s)*v) + sum(exp(s)) over its k-slice. One LDS k-row read is
//   reused for QPT queries -> LDS pipe traffic / QPT.
// FUSED=true (single slice) normalizes + projects + writes out directly.
// ---------------------------------------------------------------------------
template <int KSLICE, int QPT, bool FUSED>
__global__ __launch_bounds__(256) void attn_part_kernel(
    const float* __restrict__ x, const float* __restrict__ theta,
    const float* __restrict__ Wout, float* __restrict__ outp) {
  __shared__ float kv[KSLICE * 8];

  const int b = blockIdx.z;
  const int slice = blockIdx.y;
  const int qbase = blockIdx.x * (256 * QPT) + threadIdx.x;  // +256*g per query
  const int k0 = slice * KSLICE;

  float th[8];
#pragma unroll
  for (int e = 0; e < 8; ++e) th[e] = theta[e];

  // Stage the k-slice of h into LDS (computed on the fly from x).
  for (int r = threadIdx.x; r < KSLICE; r += 256) {
    const float4* xr = (const float4*)(x + ((size_t)b * NS + k0 + r) * 8);
    float4 lo = xr[0], hi = xr[1];
    lo.x = __cosf(lo.x + th[0]);
    lo.y = __cosf(lo.y + th[1]);
    lo.z = __cosf(lo.z + th[2]);
    lo.w = __cosf(lo.w + th[3]);
    hi.x = __cosf(hi.x + th[4]);
    hi.y = __cosf(hi.y + th[5]);
    hi.z = __cosf(hi.z + th[6]);
    hi.w = __cosf(hi.w + th[7]);
    ((float4*)kv)[2 * r] = lo;
    ((float4*)kv)[2 * r + 1] = hi;
  }

  // This thread's QPT query rows, pre-scaled by 0.5*log2(e).
  float4 qlo[QPT], qhi[QPT];
#pragma unroll
  for (int g = 0; g < QPT; ++g) {
    const float4* xq = (const float4*)(x + ((size_t)b * NS + qbase + 256 * g) * 8);
    float4 lo = xq[0], hi = xq[1];
    lo.x = __cosf(lo.x + th[0]) * QSCALE;
    lo.y = __cosf(lo.y + th[1]) * QSCALE;
    lo.z = __cosf(lo.z + th[2]) * QSCALE;
    lo.w = __cosf(lo.w + th[3]) * QSCALE;
    hi.x = __cosf(hi.x + th[4]) * QSCALE;
    hi.y = __cosf(hi.y + th[5]) * QSCALE;
    hi.z = __cosf(hi.z + th[6]) * QSCALE;
    hi.w = __cosf(hi.w + th[7]) * QSCALE;
    qlo[g] = lo;
    qhi[g] = hi;
  }

  __syncthreads();

  float4 a0[QPT], a1[QPT];
  float d0[QPT], d1[QPT];
#pragma unroll
  for (int g = 0; g < QPT; ++g) {
    a0[g] = make_float4(0.f, 0.f, 0.f, 0.f);
    a1[g] = make_float4(0.f, 0.f, 0.f, 0.f);
    d0[g] = 0.f;
    d1[g] = 0.f;
  }

  const float4* kp = (const float4*)kv;
  // Software-pipelined: prefetch row j+1 while computing row j.
  float4 kl = kp[0], kh = kp[1];
#pragma unroll 4
  for (int j = 0; j < KSLICE; ++j) {
    float4 nl, nh;
    if (j + 1 < KSLICE) {
      nl = kp[2 * (j + 1)];       // broadcast read, conflict-free
      nh = kp[2 * (j + 1) + 1];
    }
#pragma unroll
    for (int g = 0; g < QPT; ++g) {
      float s0 = qlo[g].x * kl.x + qlo[g].y * kl.y + qlo[g].z * kl.z + qlo[g].w * kl.w;
      float s1 = qhi[g].x * kh.x + qhi[g].y * kh.y + qhi[g].z * kh.z + qhi[g].w * kh.w;
      float p0 = __builtin_amdgcn_exp2f(s0);  // v_exp_f32
      float p1 = __builtin_amdgcn_exp2f(s1);
      a0[g].x += p0 * kl.x;
      a0[g].y += p0 * kl.y;
      a0[g].z += p0 * kl.z;
      a0[g].w += p0 * kl.w;
      d0[g] += p0;
      a1[g].x += p1 * kh.x;
      a1[g].y += p1 * kh.y;
      a1[g].z += p1 * kh.z;
      a1[g].w += p1 * kh.w;
      d1[g] += p1;
    }
    kl = nl;
    kh = nh;
  }

#pragma unroll
  for (int g = 0; g < QPT; ++g) {
    const int q = qbase + 256 * g;
    if (FUSED) {
      const float i0 = 1.0f / d0[g], i1 = 1.0f / d1[g];
      float m[8] = {a0[g].x * i0, a0[g].y * i0, a0[g].z * i0, a0[g].w * i0,
                    a1[g].x * i1, a1[g].y * i1, a1[g].z * i1, a1[g].w * i1};
      float o[8];
#pragma unroll
      for (int e = 0; e < 8; ++e) {
        float s = 0.f;
#pragma unroll
        for (int f = 0; f < 8; ++f) s += m[f] * Wout[e * 8 + f];
        o[e] = s;
      }
      float4* op = (float4*)(outp + ((size_t)b * NS + q) * 8);
      op[0] = make_float4(o[0], o[1], o[2], o[3]);
      op[1] = make_float4(o[4], o[5], o[6], o[7]);
    } else {
      // partial layout: [slice][component(10)][B*S]  (coalesced stores)
      const int idx = b * NS + q;
      float* p = outp + (size_t)slice * 10 * (NB * NS) + idx;
      p[0 * (NB * NS)] = a0[g].x;
      p[1 * (NB * NS)] = a0[g].y;
      p[2 * (NB * NS)] = a0[g].z;
      p[3 * (NB * NS)] = a0[g].w;
      p[4 * (NB * NS)] = a1[g].x;
      p[5 * (NB * NS)] = a1[g].y;
      p[6 * (NB * NS)] = a1[g].z;
      p[7 * (NB * NS)] = a1[g].w;
      p[8 * (NB * NS)] = d0[g];
      p[9 * (NB * NS)] = d1[g];
    }
  }
}

// ---------------------------------------------------------------------------
// Kernel B: sum slice partials, normalize, apply W_out^T, write out.
// ---------------------------------------------------------------------------
__global__ __launch_bounds__(256) void attn_reduce_kernel(
    const float* __restrict__ part, const float* __restrict__ Wout,
    float* __restrict__ out, int nslice) {
  const int idx = blockIdx.x * 256 + threadIdx.x;  // 0 .. B*S-1
  float a[10];
#pragma unroll
  for (int c = 0; c < 10; ++c) a[c] = 0.f;
  for (int sl = 0; sl < nslice; ++sl) {
    const float* p = part + (size_t)sl * 10 * (NB * NS) + idx;
#pragma unroll
    for (int c = 0; c < 10; ++c) a[c] += p[c * (NB * NS)];
  }
  const float i0 = 1.0f / a[8], i1 = 1.0f / a[9];
  float m[8] = {a[0] * i0, a[1] * i0, a[2] * i0, a[3] * i0,
                a[4] * i1, a[5] * i1, a[6] * i1, a[7] * i1};
  float o[8];
#pragma unroll
  for (int e = 0; e < 8; ++e) {
    float s = 0.f;
#pragma unroll
    for (int f = 0; f < 8; ++f) s += m[f] * Wout[e * 8 + f];
    o[e] = s;
  }
  float4* op = (float4*)(out + (size_t)idx * 8);
  op[0] = make_float4(o[0], o[1], o[2], o[3]);
  op[1] = make_float4(o[4], o[5], o[6], o[7]);
}

extern "C" void kernel_launch(void* const* d_in, const int* in_sizes, int n_in,
                              void* d_out, int out_size, void* d_ws,
                              size_t ws_size, hipStream_t stream) {
  const float* x = (const float*)d_in[0];      // [32, 2048, 8]
  const float* theta = (const float*)d_in[1];  // [8]
  const float* W = (const float*)d_in[2];      // [8, 8]
  float* out = (float*)d_out;                  // [32, 2048, 8]
  float* ws = (float*)d_ws;

  const size_t per_slice = (size_t)NB * NS * 10 * sizeof(float);  // 2.62 MB

  if (ws_size >= 8 * per_slice) {
    // 8-way split-K, 4 queries/thread: 512 blocks, 8 KB LDS.
    attn_part_kernel<256, 4, false>
        <<<dim3(NS / 1024, 8, NB), 256, 0, stream>>>(x, theta, W, ws);
    attn_reduce_kernel<<<(NB * NS) / 256, 256, 0, stream>>>(ws, W, out, 8);
  } else if (ws_size >= 4 * per_slice) {
    attn_part_kernel<512, 4, false>
        <<<dim3(NS / 1024, 4, NB), 256, 0, stream>>>(x, theta, W, ws);
    attn_reduce_kernel<<<(NB * NS) / 256, 256, 0, stream>>>(ws, W, out, 4);
  } else if (ws_size >= 2 * per_slice) {
    attn_part_kernel<1024, 4, false>
        <<<dim3(NS / 1024, 2, NB), 256, 0, stream>>>(x, theta, W, ws);
    attn_reduce_kernel<<<(NB * NS) / 256, 256, 0, stream>>>(ws, W, out, 2);
  } else {
    // Fused single-pass fallback (64 KB LDS, no workspace needed).
    attn_part_kernel<2048, 4, true>
        <<<dim3(NS / 1024, 1, NB), 256, 0, stream>>>(x, theta, W, out);
  }
}